// Round 10
// baseline (956.315 us; speedup 1.0000x reference)
//
#include <hip/hip_runtime.h>
#include <hip/hip_bf16.h>
#include <math.h>

#define ITEMS 2048
#define SEQ   64
#define DM    128
#define DFF   512
#define ATT_OFF 131072

typedef unsigned short u16;
typedef unsigned int u32;
typedef __attribute__((ext_vector_type(4))) unsigned short ushort4v;
typedef __attribute__((ext_vector_type(8))) short short8v;
typedef __attribute__((ext_vector_type(4))) float float4v;

#define MFMA16(a,b,c) __builtin_amdgcn_mfma_f32_16x16x32_bf16(a,b,c,0,0,0)

// LDS strides (u16 elements)
#define XST  136   // 272B rows, 16B-aligned, 2-way banks
#define QST1 24    // Q1/K1 rows: 48B (16 d + 8 pad), 16B-aligned
#define VST1 72    // V1T rows: 144B, 16B-aligned
#define PST  20    // P rows (scalar access only)

// arena byte offsets (single item per block/wave)
#define XS_B   0        // u16[64][136] 17408
#define Q1_B   17408    // u16[64][24]  3072
#define K1_B   20480    // u16[64][24]  3072
#define V1_B   23552    // u16[16][72]  2304
#define PL_B   25856    // u16[64][20]  2560
#define HC_B   28416    // f32[128]
#define QV_B   28928
#define OV_B   29440
#define YV_B   29952
#define Y2_B   30464
#define GW_B   30976
#define ZB_B   31488    // u16[8] zeros
#define ARENA_SZ 31504  // ~31.5KB -> ~5 blocks/CU

// tail / FFN aliases (staging regions dead by then)
#define HBF_B   17408   // FFN hidden u16[16][136] = 4352 (over Q1+K1)
#define WALLB_B 17408   // u16[8][128] bf16 = 2048
#define SALL_B  19456   // f32[512]
#define PALL_B  21504   // f32[512]
#define TALL_B  17408   // f32[1024] (wallb/sall dead)
#define FF_B    23552   // f32[512] (over V1T)

// ws layout (u16 elements)
#define WQ_O   0
#define WK_O   16384
#define WV_O   32768
#define WO_O   49152
#define UK_O   65536
#define UV_O   81920
#define W1_O   98304     // [512][128]
#define W2_O   163840    // [128][512]
#define UQ_O   229376
#define UO_O   245760
#define WGQ_O  262144
#define WGK_O  278528
#define W3_O   294912    // [512][128]
#define W4_O   360448    // [128][512]
#define WS_TOT 425984

__device__ __forceinline__ u16 f2b(float f){
  union { float f; unsigned u; } v; v.f = f;
  unsigned r = (v.u + 0x7fffu + ((v.u >> 16) & 1u)) >> 16;
  return (u16)r;
}
__device__ __forceinline__ float b2f(u16 h){
  union { unsigned u; float f; } v; v.u = ((unsigned)h) << 16;
  return v.f;
}
__device__ __forceinline__ float wsum(float v){
  #pragma unroll
  for (int off = 1; off < 64; off <<= 1) v += __shfl_xor(v, off);
  return v;
}
__device__ __forceinline__ void ln_vec(float* v, const float* g, const float* b, int lane){
  float v0 = v[lane], v1 = v[lane+64];
  float m  = wsum(v0+v1) * (1.f/128.f);
  float d0 = v0-m, d1 = v1-m;
  float var = wsum(d0*d0+d1*d1) * (1.f/128.f);
  float inv = rsqrtf(var + 1e-5f);
  v[lane]    = d0*inv*g[lane]    + b[lane];
  v[lane+64] = d1*inv*g[lane+64] + b[lane+64];
}
__device__ __forceinline__ float dot128(const u16* __restrict__ wrow, const float* __restrict__ x){
  const short8v* wr = (const short8v*)wrow;
  float a = 0.f;
  #pragma unroll
  for (int c8 = 0; c8 < 16; c8++){
    short8v v = wr[c8];
    #pragma unroll
    for (int q = 0; q < 8; q++) a += b2f((u16)v[q]) * x[c8*8+q];
  }
  return a;
}

__global__ void prep_all(const float* __restrict__ Wq, const float* __restrict__ Wk,
                         const float* __restrict__ Wv, const float* __restrict__ Wo,
                         const float* __restrict__ Uk, const float* __restrict__ Uv,
                         const float* __restrict__ W1, const float* __restrict__ W2,
                         const float* __restrict__ Uq, const float* __restrict__ Uo,
                         const float* __restrict__ Wgq, const float* __restrict__ Wgk,
                         const float* __restrict__ W3, const float* __restrict__ W4,
                         u16* __restrict__ wts){
  int idx = blockIdx.x*256 + threadIdx.x;
  if (idx >= WS_TOT) return;
  float v;
  if (idx < 98304){
    int wsel = idx >> 14, r = idx & 16383;
    const float* tab[6] = {Wq,Wk,Wv,Wo,Uk,Uv};
    int o = r >> 7, i = r & 127;
    v = tab[wsel][i*128 + o];
  } else if (idx < W2_O){
    int r = idx - W1_O; int o = r >> 7, i = r & 127;
    v = W1[i*512 + o];
  } else if (idx < UQ_O){
    int r = idx - W2_O; int o = r >> 9, i = r & 511;
    v = W2[i*128 + o];
  } else if (idx < UO_O){
    int r = idx - UQ_O; int o = r >> 7, i = r & 127;
    v = Uq[i*128 + o];
  } else if (idx < WGQ_O){
    int r = idx - UO_O; int o = r >> 7, i = r & 127;
    v = Uo[i*128 + o];
  } else if (idx < WGK_O){
    int r = idx - WGQ_O; int o = r >> 7, i = r & 127;
    v = Wgq[i*128 + o];
  } else if (idx < W3_O){
    v = Wgk[idx - WGK_O];
  } else if (idx < W4_O){
    int r = idx - W3_O; int j = r >> 7, e = r & 127;
    v = W3[e*512 + j];
  } else {
    int r = idx - W4_O; int o = r >> 9, j = r & 511;
    v = W4[j*128 + o];
  }
  wts[idx] = f2b(v);
}

__global__ void init_avg(float* __restrict__ out){
  out[ATT_OFF + blockIdx.x*256 + threadIdx.x] = 0.f;
}

__global__ __launch_bounds__(64, 2) void vicsek_fused(
    const float* __restrict__ agent_infos,
    const int*   __restrict__ nmask,
    const int*   __restrict__ pmask,
    const u16*   __restrict__ wts,
    const float* __restrict__ W_emb, const float* __restrict__ b_emb,
    const float* __restrict__ ln1g,  const float* __restrict__ ln1b,
    const float* __restrict__ b1,    const float* __restrict__ b2,
    const float* __restrict__ ln2g,  const float* __restrict__ ln2b,
    const float* __restrict__ ln3g,  const float* __restrict__ ln3b,
    const float* __restrict__ b3,    const float* __restrict__ b4,
    const float* __restrict__ ln4g,  const float* __restrict__ ln4b,
    float* __restrict__ out)
{
  __shared__ __align__(16) char arena[ARENA_SZ];
  u16* Xs  = (u16*)(arena + XS_B);
  u16* Q1  = (u16*)(arena + Q1_B);
  u16* K1  = (u16*)(arena + K1_B);
  u16* V1T = (u16*)(arena + V1_B);
  u16* Pl  = (u16*)(arena + PL_B);
  u16* zb  = (u16*)(arena + ZB_B);

  const int item = blockIdx.x;
  const int lane = threadIdx.x;      // 64-thread block = 1 wave
  const int arow = lane & 15;
  const int akg  = lane >> 4;

  const u16* WqT = wts + WQ_O;  const u16* WkT = wts + WK_O;
  const u16* WvT = wts + WV_O;  const u16* WoT = wts + WO_O;
  const u16* UkT = wts + UK_O;  const u16* UvT = wts + UV_O;
  const u16* W1T = wts + W1_O;  const u16* W2T = wts + W2_O;
  const u16* UqT = wts + UQ_O;  const u16* UoT = wts + UO_O;
  const u16* WgqT = wts + WGQ_O; const u16* WgkB = wts + WGK_O;
  const u16* W3T = wts + W3_O;  const u16* W4T = wts + W4_O;

  if (lane < 8) zb[lane] = 0;

  // ---- flags (register-resident, wave-wide) ----
  int mm = nmask[item*SEQ + lane];
  const unsigned long long nbits = __ballot(mm != 0);
  const float cnt = (float)__popcll(nbits);
  unsigned long long pb = __ballot(pmask[(item>>6)*SEQ + lane] != 0);
  const float na = (float)__popcll(pb);

  // ---- Stage A: embed (W_emb columns preloaded) ----
  {
    const float* src = agent_infos + (size_t)item*SEQ*6;
    float we0[6], we1[6];
    #pragma unroll
    for (int k = 0; k < 6; k++){ we0[k] = W_emb[k*DM+lane]; we1[k] = W_emb[k*DM+lane+64]; }
    float be0 = b_emb[lane], be1 = b_emb[lane+64];
    for (int r = 0; r < SEQ; r++){
      float a0 = be0, a1 = be1;
      #pragma unroll
      for (int k = 0; k < 6; k++){ float s = src[r*6+k]; a0 += s*we0[k]; a1 += s*we1[k]; }
      Xs[r*XST + lane]    = f2b(a0);
      Xs[r*XST + lane+64] = f2b(a1);
    }
  }

  // ---- X in registers: A-layout frags + C-layout packed residual ----
  short8v aX[4][4];
  #pragma unroll
  for (int rg = 0; rg < 4; rg++)
    #pragma unroll
    for (int k = 0; k < 4; k++)
      aX[rg][k] = *(const short8v*)(Xs + (rg*16+arow)*XST + k*32 + akg*8);
  u32 resid[4][8][2];
  #pragma unroll
  for (int rg = 0; rg < 4; rg++)
    #pragma unroll
    for (int t = 0; t < 8; t++){
      u16 x0 = Xs[(rg*16+akg*4+0)*XST + t*16+arow];
      u16 x1 = Xs[(rg*16+akg*4+1)*XST + t*16+arow];
      u16 x2 = Xs[(rg*16+akg*4+2)*XST + t*16+arow];
      u16 x3 = Xs[(rg*16+akg*4+3)*XST + t*16+arow];
      resid[rg][t][0] = (u32)x0 | ((u32)x1 << 16);
      resid[rg][t][1] = (u32)x2 | ((u32)x3 << 16);
    }

  // ---- Stage B: self-MHA, zero barriers (all same-wave) ----
  #pragma unroll 1
  for (int h = 0; h < 8; h++){
    // stage Q, K, V^T for this head (all 64 rows)
    {
      short8v bw[4];
      #pragma unroll
      for (int k = 0; k < 4; k++) bw[k] = *(const short8v*)(WqT + (h*16+arow)*128 + k*32 + akg*8);
      #pragma unroll
      for (int rg = 0; rg < 4; rg++){
        float4v c = {0,0,0,0};
        #pragma unroll
        for (int k = 0; k < 4; k++) c = MFMA16(aX[rg][k], bw[k], c);
        #pragma unroll
        for (int i = 0; i < 4; i++) Q1[(rg*16+akg*4+i)*QST1 + arow] = f2b(c[i]);
      }
      #pragma unroll
      for (int k = 0; k < 4; k++) bw[k] = *(const short8v*)(WkT + (h*16+arow)*128 + k*32 + akg*8);
      #pragma unroll
      for (int rg = 0; rg < 4; rg++){
        float4v c = {0,0,0,0};
        #pragma unroll
        for (int k = 0; k < 4; k++) c = MFMA16(aX[rg][k], bw[k], c);
        #pragma unroll
        for (int i = 0; i < 4; i++) K1[(rg*16+akg*4+i)*QST1 + arow] = f2b(c[i]);
      }
      #pragma unroll
      for (int k = 0; k < 4; k++) bw[k] = *(const short8v*)(WvT + (h*16+arow)*128 + k*32 + akg*8);
      #pragma unroll
      for (int rg = 0; rg < 4; rg++){
        float4v c = {0,0,0,0};
        #pragma unroll
        for (int k = 0; k < 4; k++) c = MFMA16(bw[k], aX[rg][k], c);   // V^T[d][key]
        #pragma unroll
        for (int i = 0; i < 4; i++) V1T[(akg*4+i)*VST1 + rg*16+arow] = f2b(c[i]);
      }
    }
    // attend: 4 q-tiles of 16
    for (int qt = 0; qt < 4; qt++){
      const u16* qp = (akg < 2) ? (Q1 + (qt*16+arow)*QST1 + akg*8) : zb;
      short8v bq = *(const short8v*)qp;
      float4v st[4];
      #pragma unroll
      for (int kb = 0; kb < 4; kb++){
        const u16* kp = (akg < 2) ? (K1 + (kb*16+arow)*QST1 + akg*8) : zb;
        float4v z = {0,0,0,0};
        st[kb] = MFMA16(*(const short8v*)kp, bq, z);
      }
      bool qok = (nbits >> (qt*16+arow)) & 1ull;
      float pr[16]; float mx = -3.0e38f;
      #pragma unroll
      for (int kb = 0; kb < 4; kb++)
        #pragma unroll
        for (int i = 0; i < 4; i++){
          int key = kb*16 + akg*4 + i;
          float s = st[kb][i]*0.25f;
          if (!qok || !((nbits>>key)&1ull)) s = -1.0e9f;
          pr[kb*4+i] = s; mx = fmaxf(mx, s);
        }
      mx = fmaxf(mx, __shfl_xor(mx,16)); mx = fmaxf(mx, __shfl_xor(mx,32));
      float sum = 0.f;
      #pragma unroll
      for (int z2 = 0; z2 < 16; z2++){ pr[z2] = __expf(pr[z2]-mx); sum += pr[z2]; }
      sum += __shfl_xor(sum,16); sum += __shfl_xor(sum,32);
      float inv = 1.f/sum;
      #pragma unroll
      for (int kb = 0; kb < 4; kb++)
        #pragma unroll
        for (int i = 0; i < 4; i++)
          Pl[(kb*16+akg*4+i)*PST + arow] = f2b(pr[kb*4+i]*inv);
      // PV: O^T = V^T @ P^T
      float4v ot = {0,0,0,0};
      #pragma unroll
      for (int c2 = 0; c2 < 2; c2++){
        short8v av = *(const short8v*)(V1T + arow*VST1 + c2*32 + akg*8);
        short8v bp;
        #pragma unroll
        for (int j = 0; j < 8; j++) bp[j] = (short)Pl[(c2*32+akg*8+j)*PST + arow];
        ot = MFMA16(av, bp, ot);
      }
      ushort4v ov4;
      #pragma unroll
      for (int i = 0; i < 4; i++) ov4[i] = f2b(ot[i]);
      *(ushort4v*)(Xs + (qt*16+arow)*XST + h*16 + akg*4) = ov4;   // O overwrites X
    }
  }

  // ---- Wo projection + residual + LN1 (per row-group, in-register LN) ----
  {
    float g8[8], bb8[8];
    #pragma unroll
    for (int t = 0; t < 8; t++){ g8[t] = ln1g[t*16+arow]; bb8[t] = ln1b[t*16+arow]; }
    #pragma unroll
    for (int rg = 0; rg < 4; rg++){
      float4v acc[8];
      #pragma unroll
      for (int t = 0; t < 8; t++){
        acc[t][0] = b2f((u16)(resid[rg][t][0] & 0xffff));
        acc[t][1] = b2f((u16)(resid[rg][t][0] >> 16));
        acc[t][2] = b2f((u16)(resid[rg][t][1] & 0xffff));
        acc[t][3] = b2f((u16)(resid[rg][t][1] >> 16));
      }
      short8v aO[4];
      #pragma unroll
      for (int k = 0; k < 4; k++) aO[k] = *(const short8v*)(Xs + (rg*16+arow)*XST + k*32 + akg*8);
      #pragma unroll
      for (int k = 0; k < 4; k++)
        #pragma unroll
        for (int t = 0; t < 8; t++)
          acc[t] = MFMA16(aO[k], *(const short8v*)(WoT + (t*16+arow)*128 + k*32 + akg*8), acc[t]);
      #pragma unroll
      for (int i = 0; i < 4; i++){
        float sm = 0.f;
        #pragma unroll
        for (int t = 0; t < 8; t++) sm += acc[t][i];
        sm += __shfl_xor(sm,1); sm += __shfl_xor(sm,2); sm += __shfl_xor(sm,4); sm += __shfl_xor(sm,8);
        float mean = sm*(1.f/128.f);
        float vs = 0.f;
        #pragma unroll
        for (int t = 0; t < 8; t++){ float d = acc[t][i]-mean; vs += d*d; }
        vs += __shfl_xor(vs,1); vs += __shfl_xor(vs,2); vs += __shfl_xor(vs,4); vs += __shfl_xor(vs,8);
        float inv = rsqrtf(vs*(1.f/128.f) + 1e-5f);
        #pragma unroll
        for (int t = 0; t < 8; t++)
          Xs[(rg*16+akg*4+i)*XST + t*16 + arow] = f2b((acc[t][i]-mean)*inv*g8[t] + bb8[t]);
      }
    }
  }

  // ---- FFN + LN2 (per row-group; hidden in Hb alias) ----
  {
    u16* Hb = (u16*)(arena + HBF_B);
    float g8[8], bb8[8];
    #pragma unroll
    for (int t = 0; t < 8; t++){ g8[t] = ln2g[t*16+arow]; bb8[t] = ln2b[t*16+arow]; }
    #pragma unroll 1
    for (int rg = 0; rg < 4; rg++){
      float4v accY[8];
      #pragma unroll
      for (int t = 0; t < 8; t++){
        float bb = b2[t*16 + arow];
        #pragma unroll
        for (int i = 0; i < 4; i++)
          accY[t][i] = bb + b2f(Xs[(rg*16+akg*4+i)*XST + t*16 + arow]);
      }
      short8v aXf[4];
      #pragma unroll
      for (int k = 0; k < 4; k++) aXf[k] = *(const short8v*)(Xs + (rg*16+arow)*XST + k*32 + akg*8);
      #pragma unroll 1
      for (int c = 0; c < 4; c++){
        #pragma unroll
        for (int t = 0; t < 8; t++){
          float bb = b1[c*128 + t*16 + arow];
          float4v hid = {bb,bb,bb,bb};
          #pragma unroll
          for (int k = 0; k < 4; k++)
            hid = MFMA16(aXf[k], *(const short8v*)(W1T + (c*128+t*16+arow)*128 + k*32 + akg*8), hid);
          #pragma unroll
          for (int i = 0; i < 4; i++)
            Hb[(akg*4+i)*XST + t*16 + arow] = f2b(fmaxf(hid[i], 0.f));
        }
        #pragma unroll
        for (int k = 0; k < 4; k++){
          short8v aH = *(const short8v*)(Hb + arow*XST + k*32 + akg*8);
          #pragma unroll
          for (int t = 0; t < 8; t++)
            accY[t] = MFMA16(aH, *(const short8v*)(W2T + (t*16+arow)*512 + c*128 + k*32 + akg*8), accY[t]);
        }
      }
      #pragma unroll
      for (int i = 0; i < 4; i++){
        float sm = 0.f;
        #pragma unroll
        for (int t = 0; t < 8; t++) sm += accY[t][i];
        sm += __shfl_xor(sm,1); sm += __shfl_xor(sm,2); sm += __shfl_xor(sm,4); sm += __shfl_xor(sm,8);
        float mean = sm*(1.f/128.f);
        float vs = 0.f;
        #pragma unroll
        for (int t = 0; t < 8; t++){ float d = accY[t][i]-mean; vs += d*d; }
        vs += __shfl_xor(vs,1); vs += __shfl_xor(vs,2); vs += __shfl_xor(vs,4); vs += __shfl_xor(vs,8);
        float inv = rsqrtf(vs*(1.f/128.f) + 1e-5f);
        #pragma unroll
        for (int t = 0; t < 8; t++)
          Xs[(rg*16+akg*4+i)*XST + t*16 + arow] = f2b((accY[t][i]-mean)*inv*g8[t] + bb8[t]);
      }
    }
  }

  // ================= tail (solo wave, no barriers) =================
  float* hc = (float*)(arena + HC_B);
  float* qv = (float*)(arena + QV_B);
  float* ov = (float*)(arena + OV_B);
  float* yv = (float*)(arena + YV_B);
  float* y2 = (float*)(arena + Y2_B);
  float* gw = (float*)(arena + GW_B);

  // h_c + global average
  {
    float a0 = 0.f, a1 = 0.f;
    for (int r = 0; r < SEQ; r++){
      float pf = ((nbits>>r)&1ull) ? 0.f : 1.f;   // pad = ~neigh
      a0 += b2f(Xs[r*XST + lane])    * pf;
      a1 += b2f(Xs[r*XST + lane+64]) * pf;
    }
    a0 /= cnt; a1 /= cnt;
    hc[lane] = a0; hc[lane+64] = a1;
    atomicAdd(&out[ATT_OFF + (item>>6)*DM + lane],    a0/na);
    atomicAdd(&out[ATT_OFF + (item>>6)*DM + lane+64], a1/na);
  }

  // qv = Uq^T h_c
  qv[lane]    = dot128(UqT + lane*128,      hc);
  qv[lane+64] = dot128(UqT + (lane+64)*128, hc);

  // wall (bf16): wall[h][e] = sum_d Uk^T[h16+d][e] * qv[h16+d]
  u16* wallb = (u16*)(arena + WALLB_B);
  #pragma unroll
  for (int half = 0; half < 2; half++){
    int e2 = lane + half*64;
    #pragma unroll
    for (int h = 0; h < 8; h++){
      float a = 0.f;
      #pragma unroll
      for (int d = 0; d < 16; d++) a += b2f(UkT[(h*16+d)*128 + e2]) * qv[h*16+d];
      wallb[h*128 + e2] = f2b(a);
    }
  }

  // sall[h][j] = (x_j . wall_h)/4 via MFMA (B cols = heads)
  float* sall = (float*)(arena + SALL_B);
  #pragma unroll
  for (int rg = 0; rg < 4; rg++){
    short8v aXf[4];
    #pragma unroll
    for (int k = 0; k < 4; k++) aXf[k] = *(const short8v*)(Xs + (rg*16+arow)*XST + k*32 + akg*8);
    float4v sc = {0,0,0,0};
    #pragma unroll
    for (int k = 0; k < 4; k++){
      short8v bw = *(const short8v*)(wallb + arow*128 + k*32 + akg*8);
      sc = MFMA16(aXf[k], bw, sc);
    }
    if (arow < 8){
      #pragma unroll
      for (int i = 0; i < 4; i++) sall[arow*64 + rg*16 + akg*4 + i] = sc[i]*0.25f;
    }
  }

  // per-head masked softmax over 64 keys
  float* pall = (float*)(arena + PALL_B);
  #pragma unroll 1
  for (int h = 0; h < 8; h++){
    float s = sall[h*64 + lane];
    if (!((nbits>>lane)&1ull)) s = -1.0e9f;
    float mxx = s;
    #pragma unroll
    for (int off = 1; off < 64; off <<= 1) mxx = fmaxf(mxx, __shfl_xor(mxx, off));
    float p = __expf(s - mxx);
    float su = wsum(p);
    pall[h*64 + lane] = p/su;
  }

  // tall[h][c] = p_h . X[:,c] via MFMA
  float* tall = (float*)(arena + TALL_B);
  #pragma unroll 1
  for (int ct = 0; ct < 8; ct++){
    float4v tc = {0,0,0,0};
    #pragma unroll
    for (int k2 = 0; k2 < 2; k2++){
      short8v ap, bx;
      #pragma unroll
      for (int j = 0; j < 8; j++){
        ap[j] = (short)f2b(pall[arow*64 + k2*32 + akg*8 + j]);   // rows>=8 junk, discarded
        bx[j] = (short)Xs[(k2*32+akg*8+j)*XST + ct*16 + arow];
      }
      tc = MFMA16(ap, bx, tc);
    }
    if (akg < 2){
      #pragma unroll
      for (int i = 0; i < 4; i++) tall[(akg*4+i)*128 + ct*16 + arow] = tc[i];
    }
  }

  // ov, yv, LN3
  ov[lane]    = dot128(UvT + lane*128,      tall + (lane>>4)*128);
  ov[lane+64] = dot128(UvT + (lane+64)*128, tall + ((lane+64)>>4)*128);
  yv[lane]    = hc[lane]    + dot128(UoT + lane*128,      ov);
  yv[lane+64] = hc[lane+64] + dot128(UoT + (lane+64)*128, ov);
  ln_vec(yv, ln3g, ln3b, lane);

  // FFN2 + LN4
  float* ff = (float*)(arena + FF_B);
  #pragma unroll 1
  for (int jj = 0; jj < 8; jj++){
    int j = jj*64 + lane;
    ff[j] = fmaxf(b3[j] + dot128(W3T + j*128, yv), 0.f);
  }
  #pragma unroll
  for (int half = 0; half < 2; half++){
    int e2 = lane + half*64;
    const short8v* wr = (const short8v*)(W4T + e2*512);
    float a = 0.f;
    #pragma unroll
    for (int c8 = 0; c8 < 64; c8++){
      short8v v = wr[c8];
      #pragma unroll
      for (int q = 0; q < 8; q++) a += b2f((u16)v[q]) * ff[c8*8+q];
    }
    y2[e2] = b4[e2] + yv[e2] + a;
  }
  ln_vec(y2, ln4g, ln4b, lane);

  // gating
  qv[lane]    = dot128(WgqT + lane*128,      y2);
  qv[lane+64] = dot128(WgqT + (lane+64)*128, y2);
  gw[lane]    = dot128(WgkB + lane*128,      qv);
  gw[lane+64] = dot128(WgkB + (lane+64)*128, qv);
  {
    float a = dot128(Xs + lane*XST, gw) * 0.08838834764831845f;   // 1/sqrt(128)
    out[(size_t)item*SEQ + lane] = ((nbits>>lane)&1ull) ? (1.f/(1.f+__expf(-a))) : 0.f;
  }
}

extern "C" void kernel_launch(void* const* d_in, const int* in_sizes, int n_in,
                              void* d_out, int out_size, void* d_ws, size_t ws_size,
                              hipStream_t stream)
{
  const float* agent_infos = (const float*)d_in[0];
  const int*   nmask       = (const int*)  d_in[1];
  const int*   pmask       = (const int*)  d_in[2];
  const float* W_emb = (const float*)d_in[4];
  const float* b_emb = (const float*)d_in[5];
  const float* Wq    = (const float*)d_in[6];
  const float* Wk    = (const float*)d_in[7];
  const float* Wv    = (const float*)d_in[8];
  const float* Wo    = (const float*)d_in[9];
  const float* ln1g  = (const float*)d_in[10];
  const float* ln1b  = (const float*)d_in[11];
  const float* W1    = (const float*)d_in[12];
  const float* b1    = (const float*)d_in[13];
  const float* W2    = (const float*)d_in[14];
  const float* b2    = (const float*)d_in[15];
  const float* ln2g  = (const float*)d_in[16];
  const float* ln2b  = (const float*)d_in[17];
  const float* Uq    = (const float*)d_in[18];
  const float* Uk    = (const float*)d_in[19];
  const float* Uv    = (const float*)d_in[20];
  const float* Uo    = (const float*)d_in[21];
  const float* ln3g  = (const float*)d_in[22];
  const float* ln3b  = (const float*)d_in[23];
  const float* W3    = (const float*)d_in[24];
  const float* b3    = (const float*)d_in[25];
  const float* W4    = (const float*)d_in[26];
  const float* b4    = (const float*)d_in[27];
  const float* ln4g  = (const float*)d_in[28];
  const float* ln4b  = (const float*)d_in[29];
  const float* Wgq   = (const float*)d_in[30];
  const float* Wgk   = (const float*)d_in[31];

  float* out = (float*)d_out;
  u16*   wts = (u16*)d_ws;   // 425984 u16 = 851968 B

  prep_all<<<(WS_TOT+255)/256, 256, 0, stream>>>(Wq, Wk, Wv, Wo, Uk, Uv, W1, W2,
                                                 Uq, Uo, Wgq, Wgk, W3, W4, wts);
  init_avg<<<16, 256, 0, stream>>>(out);
  vicsek_fused<<<ITEMS, 64, 0, stream>>>(
      agent_infos, nmask, pmask, wts, W_emb, b_emb,
      ln1g, ln1b, b1, b2, ln2g, ln2b, ln3g, ln3b,
      b3, b4, ln4g, ln4b, out);
}